// Round 10
// baseline (244.499 us; speedup 1.0000x reference)
//
#include <hip/hip_runtime.h>
#include <hip/hip_bf16.h>

#define NHEAD 16
#define DHEAD 64
#define DMODEL 1024
#define QLEN 1024
#define MEMLEN 1024
#define BSZ 2
#define KLEN 2048
#define LN_EPS 1e-5f

typedef __hip_bfloat16 bf16;
typedef __attribute__((ext_vector_type(8))) short short8;
typedef __attribute__((ext_vector_type(4))) float f32x4;

__device__ __forceinline__ float b2f(bf16 x) { return __bfloat162float(x); }
__device__ __forceinline__ bf16 f2b(float x) { return __float2bfloat16(x); }
__device__ __forceinline__ short f2bs(float f) {
    bf16 h = __float2bfloat16(f);
    return *reinterpret_cast<short*>(&h);
}
__device__ __forceinline__ float s2f(short s) {
    bf16 h = *reinterpret_cast<bf16*>(&s);
    return __bfloat162float(h);
}
// native 2^x (v_exp_f32); scores carry log2e folded in via Q scaling
__device__ __forceinline__ float fexp2(float x) {
    float y;
    asm("v_exp_f32 %0, %1" : "=v"(y) : "v"(x));
    return y;
}

#define MFMA16(a, b, c) __builtin_amdgcn_mfma_f32_16x16x32_bf16(a, b, c, 0, 0, 0)

#define AS1 __attribute__((address_space(1)))
#define AS3 __attribute__((address_space(3)))
// async global->LDS, 16B/lane; LDS dest = wave-uniform base + lane*16
__device__ __forceinline__ void gld16(const bf16* g, bf16* l) {
    __builtin_amdgcn_global_load_lds((const AS1 void*)(uintptr_t)g,
                                     (AS3 void*)(uint32_t)(uintptr_t)l, 16, 0, 0);
}

// ---------------- fused prep: flat converts + weight transposes ----------------
__global__ __launch_bounds__(256)
void prep(const float* __restrict__ mems, const float* __restrict__ w,
          const float* __restrict__ r, const float* __restrict__ Wqkv,
          const float* __restrict__ Wr, const float* __restrict__ Wo,
          bf16* __restrict__ Abf, bf16* __restrict__ rbf,
          bf16* __restrict__ Wqkvt, bf16* __restrict__ Wrt,
          bf16* __restrict__ Wot) {
    __shared__ bf16 T[64][65];
    const int id = blockIdx.x;
    const int t = threadIdx.x;
    if (id < 6144) {
        const float* src;
        bf16* dst;
        int off;
        if (id < 2048)      { src = mems; dst = Abf;                       off = id; }
        else if (id < 4096) { src = w;    dst = Abf + (size_t)2048 * 1024; off = id - 2048; }
        else                { src = r;    dst = rbf;                       off = id - 4096; }
        int i = off * 256 + t;
        const float4 v = reinterpret_cast<const float4*>(src)[i];
        bf16 o[4] = {f2b(v.x), f2b(v.y), f2b(v.z), f2b(v.w)};
        reinterpret_cast<ulong1*>(dst)[i] = *reinterpret_cast<ulong1*>(o);
        return;
    }
    int tid2 = id - 6144;
    const float* in;
    bf16* out;
    int N, tn, tile;
    if (tid2 < 768)       { in = Wqkv; out = Wqkvt; N = 3072; tn = 48; tile = tid2; }
    else if (tid2 < 1024) { in = Wr;   out = Wrt;   N = 1024; tn = 16; tile = tid2 - 768; }
    else                  { in = Wo;   out = Wot;   N = 1024; tn = 16; tile = tid2 - 1024; }
    const int K = 1024;
    const int n0 = (tile % tn) * 64, k0 = (tile / tn) * 64;
    #pragma unroll
    for (int e = 0; e < 16; e++) {
        int flat = e * 256 + t;
        int kl = flat >> 6, nl = flat & 63;
        T[kl][nl] = f2b(in[(size_t)(k0 + kl) * N + n0 + nl]);
    }
    __syncthreads();
    #pragma unroll
    for (int e = 0; e < 16; e++) {
        int flat = e * 256 + t;
        int nl = flat >> 6, kl = flat & 63;
        out[(size_t)(n0 + nl) * K + k0 + kl] = T[kl][nl];
    }
}

// ---------------- MFMA GEMM: C = A[M,K] @ Bt[N,K]^T ----------------
// BK=32 ping-pong double-buffer, ONE barrier per K-iter (R8, verified).
// mode 0 (QKV): XCD-balanced block remap (each XCD owns an 8bx x 12by rectangle
// -> per-XCD L2 footprint 5MB vs 7MB with the default 4x24 stripe); recycled Rk
// tiles; Q bias+scale fold; V in MFMA-B-fragment layout (stores ~5 txns/instr).
// mode 2: split-K f32 store (blockIdx.z picks K-half and output buffer), ldk=1024.
__global__ __launch_bounds__(256)
void gemm_mfma(const bf16* __restrict__ A, const bf16* __restrict__ Bt,
               const bf16* __restrict__ A2, const bf16* __restrict__ B2,
               int M, int N, int K, int mode,
               const float* __restrict__ rwb, const float* __restrict__ rrb,
               bf16* __restrict__ Qw, bf16* __restrict__ Qr,
               bf16* __restrict__ Kb, bf16* __restrict__ Vt,
               bf16* __restrict__ Cb, float* __restrict__ Cf,
               float* __restrict__ Cf2) {
    int bxi = blockIdx.x, byi = blockIdx.y;
    if (mode == 0) {
        // bijective XCD remap: lid -> (xcd, k); xcd owns bx in [ (xcd&3)*8, +8 ),
        // by in [ (xcd>>2)*12, +12 ). All 32x24 tiles covered exactly once.
        int lid = byi * 32 + bxi;        // hw linear dispatch order
        int xcd = lid & 7, k = lid >> 3; // 96 blocks per XCD
        bxi = (xcd & 3) * 8 + (k & 7);
        byi = (xcd >> 2) * 12 + (k >> 3);
    }
    const int bm = bxi * 128, bn = byi * 128;
    int sub = 0;
    const bf16* Ap = A;
    const bf16* Bp = Bt;
    if (mode == 0 && bm < 2048 && bn < 1024) { sub = 1; Ap = A2; Bp = B2; }
    const int ldk = (mode == 2) ? 1024 : K;       // row stride (mode2: K=512 slice)
    float* Cfz = Cf;
    if (mode == 2 && blockIdx.z) { Ap += 512; Bp += 512; Cfz = Cf2; }
    __shared__ bf16 As[2][128 * 32];
    __shared__ bf16 Bs[2][128 * 32];
    const int t = threadIdx.x;
    const int w = t >> 6, lane = t & 63, quad = lane >> 4, l16 = lane & 15;
    const int wm = (w >> 1) * 64, wn = (w & 1) * 64;
    const int lrow = lane >> 2, lcol = (lane & 3) * 8;

    auto stage = [&](int k0, int buf) {
        #pragma unroll
        for (int e = 0; e < 2; e++) {
            int ch = w + 4 * e;                   // 0..7, wave-uniform
            int row = ch * 16 + lrow;
            gld16(Ap + (size_t)(bm + row) * ldk + k0 + lcol, As[buf] + ch * 512);
            gld16(Bp + (size_t)(bn + row) * ldk + k0 + lcol, Bs[buf] + ch * 512);
        }
    };

    f32x4 acc[4][4];
    #pragma unroll
    for (int mt = 0; mt < 4; mt++)
        #pragma unroll
        for (int nt = 0; nt < 4; nt++) acc[mt][nt] = (f32x4){0.f, 0.f, 0.f, 0.f};

    stage(0, 0);
    const int NK = K >> 5;
    for (int kk = 0; kk < NK; kk++) {
        // publish stage(kk): issued one compute-phase ago (kk=0: cold, once)
        asm volatile("s_waitcnt vmcnt(0)" ::: "memory");
        __builtin_amdgcn_s_barrier();
        if (kk + 1 < NK) stage((kk + 1) << 5, (kk + 1) & 1);
        const bf16* A_ = As[kk & 1];
        const bf16* B_ = Bs[kk & 1];
        short8 af[4], bfr[4];
        #pragma unroll
        for (int mt = 0; mt < 4; mt++)
            af[mt] = *reinterpret_cast<const short8*>(&A_[(wm + 16 * mt + l16) * 32 + quad * 8]);
        #pragma unroll
        for (int nt = 0; nt < 4; nt++)
            bfr[nt] = *reinterpret_cast<const short8*>(&B_[(wn + 16 * nt + l16) * 32 + quad * 8]);
        #pragma unroll
        for (int mt = 0; mt < 4; mt++)
            #pragma unroll
            for (int nt = 0; nt < 4; nt++)
                acc[mt][nt] = MFMA16(af[mt], bfr[nt], acc[mt][nt]);
        // no trailing barrier: stage(kk+2) (which overwrites this buffer) is only
        // issued after next iter's top barrier, and its LDS writes land ~600cy
        // later -- long after this iter's ds_reads (issued before that barrier).
    }

    const float QSC = 0.18033688f;   // 0.125 * log2(e)
    #pragma unroll
    for (int mt = 0; mt < 4; mt++)
        #pragma unroll
        for (int nt = 0; nt < 4; nt++)
            #pragma unroll
            for (int r = 0; r < 4; r++) {
                int m = bm + wm + 16 * mt + quad * 4 + r;
                int c = bn + wn + 16 * nt + l16;
                float v = acc[mt][nt][r];
                if (sub) {
                    Cb[(size_t)m * 1024 + c] = f2b(v);   // Rk tile
                } else if (mode == 0) {
                    int seg = c >> 10, cc2 = c & 1023;
                    if (seg == 0) {
                        if (m >= 2048) {
                            size_t o = (size_t)(m - 2048) * 1024 + cc2;
                            Qw[o] = f2b((v + rwb[cc2]) * QSC);
                            Qr[o] = f2b((v + rrb[cc2]) * QSC);
                        }
                    } else if (seg == 1) {
                        Kb[(size_t)m * 1024 + cc2] = f2b(v);
                    } else {
                        // V in MFMA-B-fragment layout (coalesced-ish stores)
                        int j = m >> 1, bb = m & 1;
                        int vn = cc2 >> 6, dd = cc2 & 63;
                        int ds = dd >> 4, l16v = dd & 15;
                        int jt = j >> 6, jl = j & 63;
                        int h = jl >> 5, qd = (jl >> 3) & 3, e = jl & 7;
                        size_t addr = ((size_t)(vn * 2 + bb) * 32 + jt) * 4096
                                    + (ds * 2 + h) * 512 + (qd * 16 + l16v) * 8 + e;
                        Vt[addr] = f2b(v);
                    }
                } else {
                    Cfz[(size_t)m * N + c] = v;
                }
            }
}

// ---------------- MFMA flash attention: 2-publish pipelined, uniform grid ----------------
// (R8 verbatim — measured 62.1-62.6us, 76 VGPR, no spill; R9's 4-blocks/CU
// variant regressed: V is a shared operand, reg-direct costs 4x per-wave loads,
// and occupancy was not the binding constraint.)
// V staged from the fragment-layout Vt: per-lane source +lane*8, linear LDS dest,
// PV reads Vs[(ds*2+h)*512 + lane*8] (stride-16B, conflict-free, no swizzle).
// Grid 768 = 8 xcd * 96 = exactly 3 blocks/CU (LDS 50.4KB), uniform 16-17
// tiles/block via couple split at {0,17,33,49}. Per tile:
//   vmcnt(0)+barrier   <- publishes R(j+1), issued a full tile ago (~free)
//   issue V(j),K(j),R(j+2)   [single-buffer V,K; ring-3 R]
//   BD (10 MFMA, ~350cy, covers K/V flight)
//   vmcnt(2)+barrier   <- publishes V(j),K(j); R(j+2) stays in flight
//   AC, softmax(exp2, defer-max log2-THR), P->Pb, PV
__global__ __launch_bounds__(256, 3)
void attn_mfma(const bf16* __restrict__ Qw, const bf16* __restrict__ Qr,
               const bf16* __restrict__ Kb, const bf16* __restrict__ Vt,
               const bf16* __restrict__ Rk, float* __restrict__ O0g,
               float* __restrict__ O1g, float2* __restrict__ ML) {
    const int id = blockIdx.x;
    const int xcd = id & 7, local = id >> 3;          // local 0..95
    const int pidx = local & 3;
    const int couple = (local >> 2) & 7;
    const int chunk = local >> 5;                     // 0..2
    const int pair = xcd * 4 + pidx;                  // pinned per XCD
    const int b = pair & 1, n = pair >> 1;
    const int TA = couple + 17;
    const int t_beg = (chunk == 0) ? 0 : (chunk == 1) ? 17 : 33;
    const int t_end = (chunk == 0) ? 17 : (chunk == 1) ? 33 : 49;

    // segment table: {i0, jbeg, jend, slot}
    int segs[2][4];
    int nseg = 0;
    {
        int aend = min(t_end, TA);
        if (t_beg < aend) {
            segs[nseg][0] = couple; segs[nseg][1] = t_beg;
            segs[nseg][2] = aend;   segs[nseg][3] = (t_beg == 0) ? 0 : 1;
            nseg++;
        }
        int bbeg = max(t_beg, TA);
        if (bbeg < t_end) {
            segs[nseg][0] = 15 - couple; segs[nseg][1] = bbeg - TA;
            segs[nseg][2] = t_end - TA;  segs[nseg][3] = (bbeg == TA) ? 0 : 1;
            nseg++;
        }
    }

    const int tid = threadIdx.x;
    const int w = tid >> 6, lane = tid & 63;
    const int quad = lane >> 4, l16 = lane & 15;
    const int ln8 = lane >> 3;
    const int cs = (lane & 7) ^ (ln8 & 7);            // swizzled source chunk (K,R)
    const int q0 = (quad ^ (l16 & 7)) * 8;            // frag chunk (k 0..31)
    const int q1 = q0 ^ 32;
    const int rbl = 48 - 16 * w;

    __shared__ bf16 Ks[64 * 64];
    __shared__ bf16 Vs[64 * 64];                      // fragment-layout tile
    __shared__ bf16 Rs[3][64 * 64];                   // ring of 64-row halves
    __shared__ short WP_s[4][16 * 82];   // per-wave: WlB stride 82 / Pb stride 72
    short* WP = WP_s[w];

    const int koff = b * 1024 + n * 64 + cs * 8;
    const bf16* Vbase = Vt + (size_t)(n * 2 + b) * 131072 + lane * 8;
    const int rcol = n * 64 + cs * 8;

    for (int sg = 0; sg < nseg; sg++) {
        const int i0 = segs[sg][0], jb = segs[sg][1], je = segs[sg][2], slot = segs[sg][3];
        const int I0 = i0 * 64;
        const int qbase = I0 + 16 * w;
        const int RB = 960 - I0;
        const int jlast = i0 + 16;                    // only tile needing the mask

        auto stageKV = [&](int tt) {
            const int J0t = tt * 64;
            const bf16* vt = Vbase + (size_t)tt * 4096;
            #pragma unroll
            for (int e = 0; e < 2; e++) {
                int ch = w + 4 * e;
                gld16(vt + ch * 512, Vs + ch * 512);
                gld16(Kb + (size_t)(J0t + ch * 8 + ln8) * 2048 + koff, Ks + ch * 512);
            }
        };
        auto stageR = [&](int u) {
            bf16* rd = Rs[u % 3];
            #pragma unroll
            for (int e = 0; e < 2; e++) {
                int ch = w + 4 * e;
                int rrow = min(RB + u * 64 + ch * 8 + ln8, 2047);  // OOB -> masked pairs only
                gld16(Rk + (size_t)rrow * 1024 + rcol, rd + ch * 512);
            }
        };

        short8 aqw[2], aqr[2];
        {
            const bf16* qp = Qw + ((size_t)(qbase + l16) * 2 + b) * 1024 + n * 64 + quad * 8;
            aqw[0] = *reinterpret_cast<const short8*>(qp);
            aqw[1] = *reinterpret_cast<const short8*>(qp + 32);
            const bf16* qp2 = Qr + ((size_t)(qbase + l16) * 2 + b) * 1024 + n * 64 + quad * 8;
            aqr[0] = *reinterpret_cast<const short8*>(qp2);
            aqr[1] = *reinterpret_cast<const short8*>(qp2 + 32);
        }

        f32x4 O[4];
        #pragma unroll
        for (int d = 0; d < 4; d++) O[d] = (f32x4){0.f, 0.f, 0.f, 0.f};
        float m_run = -1e30f;
        float pl[4] = {0.f, 0.f, 0.f, 0.f};

        // segment prologue: (sg>0) make sure nobody still reads old buffers,
        // then seed the R ring with halves jb, jb+1.
        if (sg) {
            asm volatile("s_waitcnt vmcnt(0)" ::: "memory");
            __builtin_amdgcn_s_barrier();
        }
        stageR(jb); stageR(jb + 1);

        for (int j = jb; j < je; j++) {
            const int J0 = j * 64;

            // publish R(j+1) (and all older): issued a full tile ago -> ~free
            asm volatile("s_waitcnt vmcnt(0)" ::: "memory");
            __builtin_amdgcn_s_barrier();

            // issue this tile's V,K and next-next R half
            stageKV(j);
            stageR(j + 2);

            const bf16* R0 = Rs[j % 3];
            const bf16* R1 = Rs[(j + 1) % 3];

            // ---- BD window GEMM from R halves (covers K/V flight time) ----
            #pragma unroll
            for (int s = 0; s < 5; s++) {
                int rb2 = rbl + 16 * s;                   // 0..112, 16-aligned
                const bf16* Rb = (rb2 & 64) ? R1 : R0;
                int rh = (rb2 & 63) + l16;
                short8 b0 = *reinterpret_cast<const short8*>(&Rb[rh * 64 + q0]);
                short8 b1 = *reinterpret_cast<const short8*>(&Rb[rh * 64 + q1]);
                f32x4 acc = (f32x4){0.f, 0.f, 0.f, 0.f};
                __builtin_amdgcn_s_setprio(1);
                acc = MFMA16(aqr[0], b0, acc);
                acc = MFMA16(aqr[1], b1, acc);
                __builtin_amdgcn_s_setprio(0);
                #pragma unroll
                for (int r = 0; r < 4; r++)
                    WP[(quad * 4 + r) * 82 + 16 * s + l16] = f2bs(acc[r]);
            }

            // publish V(j),K(j); leave R(j+2) (2 newest ops) in flight
            asm volatile("s_waitcnt vmcnt(2)" ::: "memory");
            __builtin_amdgcn_s_barrier();

            // ---- AC GEMM from Ks + score assembly (pre-scaled, mask last tile only) ----
            float sv[4][4];
            #pragma unroll
            for (int n16 = 0; n16 < 4; n16++) {
                int kr = 16 * n16 + l16;
                short8 k0 = *reinterpret_cast<const short8*>(&Ks[kr * 64 + q0]);
                short8 k1 = *reinterpret_cast<const short8*>(&Ks[kr * 64 + q1]);
                f32x4 acc = (f32x4){0.f, 0.f, 0.f, 0.f};
                __builtin_amdgcn_s_setprio(1);
                acc = MFMA16(aqw[0], k0, acc);
                acc = MFMA16(aqw[1], k1, acc);
                __builtin_amdgcn_s_setprio(0);
                #pragma unroll
                for (int r = 0; r < 4; r++) {
                    int row = quad * 4 + r, col = 16 * n16 + l16;
                    sv[n16][r] = acc[r] + s2f(WP[row * 82 + col - row + 15]);
                }
            }
            if (j == jlast) {
                #pragma unroll
                for (int n16 = 0; n16 < 4; n16++)
                    #pragma unroll
                    for (int r = 0; r < 4; r++) {
                        int row = quad * 4 + r, col = 16 * n16 + l16;
                        if (J0 + col > qbase + row + MEMLEN) sv[n16][r] = -1e30f;
                    }
            }

            // ---- online softmax in log2 domain (defer-max, THR=11.5 bits) ----
            float mx = sv[0][0];
            #pragma unroll
            for (int n16 = 0; n16 < 4; n16++)
                #pragma unroll
                for (int r = 0; r < 4; r++) mx = fmaxf(mx, sv[n16][r]);
            #pragma unroll
            for (int msk = 1; msk < 16; msk <<= 1) mx = fmaxf(mx, __shfl_xor(mx, msk));
            if (mx > m_run + 11.5f) {
                const float alpha = fexp2(m_run - mx);
                m_run = mx;
                #pragma unroll
                for (int r = 0; r < 4; r++) pl[r] *= alpha;
                #pragma unroll
                for (int d = 0; d < 4; d++)
                    #pragma unroll
                    for (int r = 0; r < 4; r++) O[d][r] *= alpha;
            }
            #pragma unroll
            for (int n16 = 0; n16 < 4; n16++)
                #pragma unroll
                for (int r = 0; r < 4; r++) sv[n16][r] = fexp2(sv[n16][r] - m_run);
            #pragma unroll
            for (int r = 0; r < 4; r++)
                pl[r] += sv[0][r] + sv[1][r] + sv[2][r] + sv[3][r];

            // ---- P -> per-wave LDS bf16 (stride 72), read back as A-frags ----
            #pragma unroll
            for (int n16 = 0; n16 < 4; n16++)
                #pragma unroll
                for (int r = 0; r < 4; r++)
                    WP[(quad * 4 + r) * 72 + 16 * n16 + l16] = f2bs(sv[n16][r]);
            short8 ap0 = *reinterpret_cast<short8*>(&WP[l16 * 72 + quad * 8]);
            short8 ap1 = *reinterpret_cast<short8*>(&WP[l16 * 72 + 32 + quad * 8]);

            // ---- PV from Vs (fragment layout: linear, conflict-free) ----
            __builtin_amdgcn_s_setprio(1);
            #pragma unroll
            for (int ds = 0; ds < 4; ds++) {
                short8 v0 = *reinterpret_cast<const short8*>(&Vs[(ds * 2 + 0) * 512 + lane * 8]);
                short8 v1 = *reinterpret_cast<const short8*>(&Vs[(ds * 2 + 1) * 512 + lane * 8]);
                O[ds] = MFMA16(ap0, v0, O[ds]);
                O[ds] = MFMA16(ap1, v1, O[ds]);
            }
            __builtin_amdgcn_s_setprio(0);
        }

        // ---- flush segment partial (UNNORMALIZED O + (m,l)), m in log2 domain ----
        float lr[4];
        #pragma unroll
        for (int r = 0; r < 4; r++) {
            float s = pl[r];
            #pragma unroll
            for (int msk = 1; msk < 16; msk <<= 1) s += __shfl_xor(s, msk);
            lr[r] = s;
        }
        if (l16 == 0) {
            #pragma unroll
            for (int r = 0; r < 4; r++) {
                int q = qbase + quad * 4 + r;
                ML[(size_t)slot * 32768 + (q * 2 + b) * 16 + n] =
                    make_float2(m_run, lr[r]);
            }
        }
        float* Od = slot ? O1g : O0g;
        #pragma unroll
        for (int ds = 0; ds < 4; ds++)
            #pragma unroll
            for (int r = 0; r < 4; r++) {
                int q = qbase + quad * 4 + r;
                Od[((size_t)q * 2 + b) * 1024 + n * 64 + 16 * ds + l16] = O[ds][r];
            }
    }
}

// ---------------- combine split partials -> AVbf (bf16) ----------------
// q-tile i0 = row>>7: i0==0 has only slot0; all others have slots {0,1}.
// m values are in log2 domain (exp2 weights).
__global__ __launch_bounds__(256)
void attn_combine(const float* __restrict__ O0, const float* __restrict__ O1,
                  const float2* __restrict__ ML, bf16* __restrict__ AVbf) {
    const int row = blockIdx.x;       // q*2+b, 0..2047
    const int t = threadIdx.x;        // 4 cols per thread
    const int n = t >> 4;
    const int i0 = row >> 7;
    const float2 a0 = ML[row * 16 + n];
    const f32x4 p0 = reinterpret_cast<const f32x4*>(O0)[row * 256 + t];
    short o[4];
    if (i0 != 0) {
        const float2 a1 = ML[32768 + row * 16 + n];
        const float m = fmaxf(a0.x, a1.x);
        const float e0 = fexp2(a0.x - m);
        const float e1 = fexp2(a1.x - m);
        const float inv = 1.f / (a0.y * e0 + a1.y * e1);
        const f32x4 p1 = reinterpret_cast<const f32x4*>(O1)[row * 256 + t];
        #pragma unroll
        for (int jj = 0; jj < 4; jj++)
            o[jj] = f2bs((p0[jj] * e0 + p1[jj] * e1) * inv);
    } else {
        const float inv = 1.f / a0.y;
        #pragma unroll
        for (int jj = 0; jj < 4; jj++) o[jj] = f2bs(p0[jj] * inv);
    }
    reinterpret_cast<ulong1*>(AVbf)[row * 256 + t] = *reinterpret_cast<ulong1*>(o);
}

// ---------------- out = LN(ao0 + ao1 + w), f32; wave-shuffle reduction ----------------
__global__ __launch_bounds__(256)
void ln_res(const float* __restrict__ ao0, const float* __restrict__ ao1,
            const float* __restrict__ w, const float* __restrict__ gamma,
            const float* __restrict__ beta, float* __restrict__ out) {
    const int m = blockIdx.x;
    const int t = threadIdx.x;
    const int wv = t >> 6, lane = t & 63;
    __shared__ float red[8];
    float x[4];
    #pragma unroll
    for (int e = 0; e < 4; e++) {
        int c = e * 256 + t;
        x[e] = ao0[(size_t)m * DMODEL + c] + ao1[(size_t)m * DMODEL + c]
             + w[(size_t)m * DMODEL + c];
    }
    float s = x[0] + x[1] + x[2] + x[3];
    #pragma unroll
    for (int msk = 1; msk < 64; msk <<= 1) s += __shfl_xor(s, msk);
    if (lane == 0) red[wv] = s;
    __syncthreads();
    const float mu = (red[0] + red[1] + red[2] + red[3]) * (1.f / 1024.f);
    float s2 = 0.f;
    #pragma unroll
    for (int e = 0; e < 4; e++) { float dx = x[e] - mu; s2 += dx * dx; }
    #pragma unroll
    for (int msk = 1; msk < 64; msk <<= 1) s2 += __shfl_xor(s2, msk);
    if (lane == 0) red[4 + wv] = s2;
    __syncthreads();
    const float rstd = rsqrtf((red[4] + red[5] + red[6] + red[7]) * (1.f / 1024.f) + LN_EPS);
    #pragma unroll
    for (int e = 0; e < 4; e++) {
        int c = e * 256 + t;
        out[(size_t)m * DMODEL + c] = (x[e] - mu) * rstd * gamma[c] + beta[c];
    }
}

extern "C" void kernel_launch(void* const* d_in, const int* in_sizes, int n_in,
                              void* d_out, int out_size, void* d_ws, size_t ws_size,
                              hipStream_t stream) {
    const float* w        = (const float*)d_in[0];
    const float* r        = (const float*)d_in[1];
    const float* r_w_bias = (const float*)d_in[2];
    const float* r_r_bias = (const float*)d_in[3];
    const float* mems     = (const float*)d_in[4];
    // d_in[5] attn_mask: deterministic (j <= i+MEMLEN), applied analytically
    const float* W_qkv    = (const float*)d_in[6];
    const float* W_r      = (const float*)d_in[7];
    const float* W_o      = (const float*)d_in[8];
    const float* gamma    = (const float*)d_in[9];
    const float* beta     = (const float*)d_in[10];
    float* out = (float*)d_out;

    // Workspace (~54 MB). Dead-region aliases during attention:
    //   Opart0 (f32 [2048,1024] = 8MB) = Abf         (dead after QKV GEMM)
    //   Opart1 (f32 [2048,1024] = 8MB) = Wqkvt+Wrt   (dead after QKV GEMM)
    //   ML     (f32x2 [2,2048,16])     = rbf         (dead after QKV GEMM)
    //   attn_out0/1 f32 = Abf / Wqkvt (written by split-K Wo-GEMM AFTER combine
    //   consumed Opart0/Opart1)
    bf16* Abf    = (bf16*)d_ws;                    // [4096,1024] cat rows m=j*2+b
    bf16* Wqkvt  = Abf   + (size_t)4096 * 1024;    // [3072,1024]
    bf16* Wrt    = Wqkvt + (size_t)3072 * 1024;    // [1024,1024]
    bf16* Wot    = Wrt   + (size_t)1024 * 1024;    // [1024,1024]
    bf16* rbf    = Wot   + (size_t)1024 * 1024;    // [2048,1024]
    bf16* Qw     = rbf   + (size_t)2048 * 1024;    // [2048,1024] rows i*2+b
    bf16* Qr     = Qw    + (size_t)2048 * 1024;
    bf16* Kb     = Qr    + (size_t)2048 * 1024;    // [4096,1024] rows j*2+b
    bf16* Vt     = Kb    + (size_t)4096 * 1024;    // [2048,2048] fragment layout
    bf16* Rk     = Vt    + (size_t)2048 * 2048;    // [2048,1024]
    bf16* AVbf   = Rk    + (size_t)2048 * 1024;    // [2048,1024]
    float* Opart0   = (float*)Abf;                 // [2048,1024] f32 (alias)
    float* Opart1   = (float*)Wqkvt;               // [2048,1024] f32 (alias, spans Wqkvt+Wrt)
    float2* ML      = (float2*)rbf;                // [2,2048,16] (alias)
    float* attn_out0 = (float*)Abf;                // split-K half 0
    float* attn_out1 = (float*)Wqkvt;              // split-K half 1

    dim3 b256(256);
    prep<<<dim3(7424), b256, 0, stream>>>(mems, w, r, W_qkv, W_r, W_o,
                                          Abf, rbf, Wqkvt, Wrt, Wot);
    // QKV GEMM (+ recycled Rk tiles, + V fragment-layout writes, + XCD remap)
    gemm_mfma<<<dim3(32, 24), b256, 0, stream>>>(
        Abf, Wqkvt, rbf, Wrt, 4096, 3072, 1024, 0, r_w_bias, r_r_bias,
        Qw, Qr, Kb, Vt, Rk, nullptr, nullptr);
    attn_mfma<<<dim3(768), b256, 0, stream>>>(Qw, Qr, Kb, Vt, Rk,
                                              Opart0, Opart1, ML);
    attn_combine<<<dim3(2048), b256, 0, stream>>>(Opart0, Opart1, ML, AVbf);
    // Wo GEMM, split-K2: 256 blocks (full GPU), halves summed in ln_res
    gemm_mfma<<<dim3(16, 8, 2), b256, 0, stream>>>(
        AVbf, Wot, nullptr, nullptr, 2048, 1024, 512, 2, nullptr, nullptr,
        nullptr, nullptr, nullptr, nullptr, nullptr, attn_out0, attn_out1);
    ln_res<<<dim3(QLEN * BSZ), b256, 0, stream>>>(attn_out0, attn_out1, w,
                                                  gamma, beta, out);
}

// Round 11
// 238.951 us; speedup vs baseline: 1.0232x; 1.0232x over previous
//
#include <hip/hip_runtime.h>
#include <hip/hip_bf16.h>

#define NHEAD 16
#define DHEAD 64
#define DMODEL 1024
#define QLEN 1024
#define MEMLEN 1024
#define BSZ 2
#define KLEN 2048
#define LN_EPS 1e-5f

typedef __hip_bfloat16 bf16;
typedef __attribute__((ext_vector_type(8))) short short8;
typedef __attribute__((ext_vector_type(4))) float f32x4;

__device__ __forceinline__ float b2f(bf16 x) { return __bfloat162float(x); }
__device__ __forceinline__ bf16 f2b(float x) { return __float2bfloat16(x); }
__device__ __forceinline__ short f2bs(float f) {
    bf16 h = __float2bfloat16(f);
    return *reinterpret_cast<short*>(&h);
}
__device__ __forceinline__ float s2f(short s) {
    bf16 h = *reinterpret_cast<bf16*>(&s);
    return __bfloat162float(h);
}
// native 2^x (v_exp_f32); scores carry log2e folded in via Q scaling
__device__ __forceinline__ float fexp2(float x) {
    float y;
    asm("v_exp_f32 %0, %1" : "=v"(y) : "v"(x));
    return y;
}

#define MFMA16(a, b, c) __builtin_amdgcn_mfma_f32_16x16x32_bf16(a, b, c, 0, 0, 0)

#define AS1 __attribute__((address_space(1)))
#define AS3 __attribute__((address_space(3)))
// async global->LDS, 16B/lane; LDS dest = wave-uniform base + lane*16
__device__ __forceinline__ void gld16(const bf16* g, bf16* l) {
    __builtin_amdgcn_global_load_lds((const AS1 void*)(uintptr_t)g,
                                     (AS3 void*)(uint32_t)(uintptr_t)l, 16, 0, 0);
}

// ---------------- fused prep: flat converts + weight transposes ----------------
__global__ __launch_bounds__(256)
void prep(const float* __restrict__ mems, const float* __restrict__ w,
          const float* __restrict__ r, const float* __restrict__ Wqkv,
          const float* __restrict__ Wr, const float* __restrict__ Wo,
          bf16* __restrict__ Abf, bf16* __restrict__ rbf,
          bf16* __restrict__ Wqkvt, bf16* __restrict__ Wrt,
          bf16* __restrict__ Wot) {
    __shared__ bf16 T[64][65];
    const int id = blockIdx.x;
    const int t = threadIdx.x;
    if (id < 6144) {
        const float* src;
        bf16* dst;
        int off;
        if (id < 2048)      { src = mems; dst = Abf;                       off = id; }
        else if (id < 4096) { src = w;    dst = Abf + (size_t)2048 * 1024; off = id - 2048; }
        else                { src = r;    dst = rbf;                       off = id - 4096; }
        int i = off * 256 + t;
        const float4 v = reinterpret_cast<const float4*>(src)[i];
        bf16 o[4] = {f2b(v.x), f2b(v.y), f2b(v.z), f2b(v.w)};
        reinterpret_cast<ulong1*>(dst)[i] = *reinterpret_cast<ulong1*>(o);
        return;
    }
    int tid2 = id - 6144;
    const float* in;
    bf16* out;
    int N, tn, tile;
    if (tid2 < 768)       { in = Wqkv; out = Wqkvt; N = 3072; tn = 48; tile = tid2; }
    else if (tid2 < 1024) { in = Wr;   out = Wrt;   N = 1024; tn = 16; tile = tid2 - 768; }
    else                  { in = Wo;   out = Wot;   N = 1024; tn = 16; tile = tid2 - 1024; }
    const int K = 1024;
    const int n0 = (tile % tn) * 64, k0 = (tile / tn) * 64;
    #pragma unroll
    for (int e = 0; e < 16; e++) {
        int flat = e * 256 + t;
        int kl = flat >> 6, nl = flat & 63;
        T[kl][nl] = f2b(in[(size_t)(k0 + kl) * N + n0 + nl]);
    }
    __syncthreads();
    #pragma unroll
    for (int e = 0; e < 16; e++) {
        int flat = e * 256 + t;
        int nl = flat >> 6, kl = flat & 63;
        out[(size_t)(n0 + nl) * K + k0 + kl] = T[kl][nl];
    }
}

// ---------------- QKV MFMA GEMM: depth-2 pipelined, BK=32, 3 LDS buffers ----------------
// K=1024 fixed. Top-of-iter s_waitcnt vmcnt(4) retires ONLY stage(kk) (issued two
// iters ago, FIFO), leaving stage(kk+1)'s 4 ops in flight -> loads get 2 compute
// phases + 2 barriers to land (R8's vmcnt(0)-at-top exposed ~half the latency).
// LDS 48KB -> 3 blocks/CU. Epilogue: recycled Rk tiles; Q bias+scale fold
// (0.125*log2e); V in MFMA-B-fragment layout (stores ~5 txns/instr).
__global__ __launch_bounds__(256)
void gemm_qkv(const bf16* __restrict__ A, const bf16* __restrict__ Bt,
              const bf16* __restrict__ A2, const bf16* __restrict__ B2,
              const float* __restrict__ rwb, const float* __restrict__ rrb,
              bf16* __restrict__ Qw, bf16* __restrict__ Qr,
              bf16* __restrict__ Kb, bf16* __restrict__ Vt,
              bf16* __restrict__ Cb) {
    const int bm = blockIdx.x * 128, bn = blockIdx.y * 128;
    int sub = 0;
    const bf16* Ap = A;
    const bf16* Bp = Bt;
    if (bm < 2048 && bn < 1024) { sub = 1; Ap = A2; Bp = B2; }
    __shared__ bf16 As[3][128 * 32];
    __shared__ bf16 Bs[3][128 * 32];
    const int t = threadIdx.x;
    const int w = t >> 6, lane = t & 63, quad = lane >> 4, l16 = lane & 15;
    const int wm = (w >> 1) * 64, wn = (w & 1) * 64;
    const int lrow = lane >> 2, lcol = (lane & 3) * 8;

    auto stage = [&](int k0, int buf) {
        #pragma unroll
        for (int e = 0; e < 2; e++) {
            int ch = w + 4 * e;                   // 0..7, wave-uniform
            int row = ch * 16 + lrow;
            gld16(Ap + (size_t)(bm + row) * 1024 + k0 + lcol, As[buf] + ch * 512);
            gld16(Bp + (size_t)(bn + row) * 1024 + k0 + lcol, Bs[buf] + ch * 512);
        }
    };

    f32x4 acc[4][4];
    #pragma unroll
    for (int mt = 0; mt < 4; mt++)
        #pragma unroll
        for (int nt = 0; nt < 4; nt++) acc[mt][nt] = (f32x4){0.f, 0.f, 0.f, 0.f};

    stage(0, 0);
    stage(32, 1);
    const int NK = 32;                            // K=1024, BK=32
    for (int kk = 0; kk < NK; kk++) {
        // retire stage(kk) only; stage(kk+1) (newest 4 ops) stays in flight
        if (kk + 1 < NK) asm volatile("s_waitcnt vmcnt(4)" ::: "memory");
        else             asm volatile("s_waitcnt vmcnt(0)" ::: "memory");
        __builtin_amdgcn_s_barrier();
        if (kk + 2 < NK) stage((kk + 2) << 5, (kk + 2) % 3);
        const bf16* A_ = As[kk % 3];
        const bf16* B_ = Bs[kk % 3];
        short8 af[4], bfr[4];
        #pragma unroll
        for (int mt = 0; mt < 4; mt++)
            af[mt] = *reinterpret_cast<const short8*>(&A_[(wm + 16 * mt + l16) * 32 + quad * 8]);
        #pragma unroll
        for (int nt = 0; nt < 4; nt++)
            bfr[nt] = *reinterpret_cast<const short8*>(&B_[(wn + 16 * nt + l16) * 32 + quad * 8]);
        #pragma unroll
        for (int mt = 0; mt < 4; mt++)
            #pragma unroll
            for (int nt = 0; nt < 4; nt++)
                acc[mt][nt] = MFMA16(af[mt], bfr[nt], acc[mt][nt]);
        // buffer (kk+2)%3 being staged was read in iter kk-1; all its ds_reads
        // were consumed (waitcnt'd before MFMA) before any wave passed this
        // iter's top barrier -> safe.
    }

    const float QSC = 0.18033688f;   // 0.125 * log2(e)
    #pragma unroll
    for (int mt = 0; mt < 4; mt++)
        #pragma unroll
        for (int nt = 0; nt < 4; nt++)
            #pragma unroll
            for (int r = 0; r < 4; r++) {
                int m = bm + wm + 16 * mt + quad * 4 + r;
                int c = bn + wn + 16 * nt + l16;
                float v = acc[mt][nt][r];
                if (sub) {
                    Cb[(size_t)m * 1024 + c] = f2b(v);   // Rk tile
                } else {
                    int seg = c >> 10, cc2 = c & 1023;
                    if (seg == 0) {
                        if (m >= 2048) {
                            size_t o = (size_t)(m - 2048) * 1024 + cc2;
                            Qw[o] = f2b((v + rwb[cc2]) * QSC);
                            Qr[o] = f2b((v + rrb[cc2]) * QSC);
                        }
                    } else if (seg == 1) {
                        Kb[(size_t)m * 1024 + cc2] = f2b(v);
                    } else {
                        // V in MFMA-B-fragment layout (coalesced-ish stores)
                        int j = m >> 1, bb = m & 1;
                        int vn = cc2 >> 6, dd = cc2 & 63;
                        int ds = dd >> 4, l16v = dd & 15;
                        int jt = j >> 6, jl = j & 63;
                        int h = jl >> 5, qd = (jl >> 3) & 3, e = jl & 7;
                        size_t addr = ((size_t)(vn * 2 + bb) * 32 + jt) * 4096
                                    + (ds * 2 + h) * 512 + (qd * 16 + l16v) * 8 + e;
                        Vt[addr] = f2b(v);
                    }
                }
            }
}

// ---------------- MFMA flash attention: 2-publish pipelined, uniform grid ----------------
// (R8 verbatim — measured 62.1-62.6us, 76 VGPR, no spill.)
// V staged from the fragment-layout Vt: per-lane source +lane*8, linear LDS dest,
// PV reads Vs[(ds*2+h)*512 + lane*8] (stride-16B, conflict-free, no swizzle).
// Grid 768 = 8 xcd * 96 = exactly 3 blocks/CU (LDS 50.4KB), uniform 16-17
// tiles/block via couple split at {0,17,33,49}. Per tile:
//   vmcnt(0)+barrier   <- publishes R(j+1), issued a full tile ago (~free)
//   issue V(j),K(j),R(j+2)   [single-buffer V,K; ring-3 R]
//   BD (10 MFMA, ~350cy, covers K/V flight)
//   vmcnt(2)+barrier   <- publishes V(j),K(j); R(j+2) stays in flight
//   AC, softmax(exp2, defer-max log2-THR), P->Pb, PV
__global__ __launch_bounds__(256, 3)
void attn_mfma(const bf16* __restrict__ Qw, const bf16* __restrict__ Qr,
               const bf16* __restrict__ Kb, const bf16* __restrict__ Vt,
               const bf16* __restrict__ Rk, float* __restrict__ O0g,
               float* __restrict__ O1g, float2* __restrict__ ML) {
    const int id = blockIdx.x;
    const int xcd = id & 7, local = id >> 3;          // local 0..95
    const int pidx = local & 3;
    const int couple = (local >> 2) & 7;
    const int chunk = local >> 5;                     // 0..2
    const int pair = xcd * 4 + pidx;                  // pinned per XCD
    const int b = pair & 1, n = pair >> 1;
    const int TA = couple + 17;
    const int t_beg = (chunk == 0) ? 0 : (chunk == 1) ? 17 : 33;
    const int t_end = (chunk == 0) ? 17 : (chunk == 1) ? 33 : 49;

    // segment table: {i0, jbeg, jend, slot}
    int segs[2][4];
    int nseg = 0;
    {
        int aend = min(t_end, TA);
        if (t_beg < aend) {
            segs[nseg][0] = couple; segs[nseg][1] = t_beg;
            segs[nseg][2] = aend;   segs[nseg][3] = (t_beg == 0) ? 0 : 1;
            nseg++;
        }
        int bbeg = max(t_beg, TA);
        if (bbeg < t_end) {
            segs[nseg][0] = 15 - couple; segs[nseg][1] = bbeg - TA;
            segs[nseg][2] = t_end - TA;  segs[nseg][3] = (bbeg == TA) ? 0 : 1;
            nseg++;
        }
    }

    const int tid = threadIdx.x;
    const int w = tid >> 6, lane = tid & 63;
    const int quad = lane >> 4, l16 = lane & 15;
    const int ln8 = lane >> 3;
    const int cs = (lane & 7) ^ (ln8 & 7);            // swizzled source chunk (K,R)
    const int q0 = (quad ^ (l16 & 7)) * 8;            // frag chunk (k 0..31)
    const int q1 = q0 ^ 32;
    const int rbl = 48 - 16 * w;

    __shared__ bf16 Ks[64 * 64];
    __shared__ bf16 Vs[64 * 64];                      // fragment-layout tile
    __shared__ bf16 Rs[3][64 * 64];                   // ring of 64-row halves
    __shared__ short WP_s[4][16 * 82];   // per-wave: WlB stride 82 / Pb stride 72
    short* WP = WP_s[w];

    const int koff = b * 1024 + n * 64 + cs * 8;
    const bf16* Vbase = Vt + (size_t)(n * 2 + b) * 131072 + lane * 8;
    const int rcol = n * 64 + cs * 8;

    for (int sg = 0; sg < nseg; sg++) {
        const int i0 = segs[sg][0], jb = segs[sg][1], je = segs[sg][2], slot = segs[sg][3];
        const int I0 = i0 * 64;
        const int qbase = I0 + 16 * w;
        const int RB = 960 - I0;
        const int jlast = i0 + 16;                    // only tile needing the mask

        auto stageKV = [&](int tt) {
            const int J0t = tt * 64;
            const bf16* vt = Vbase + (size_t)tt * 4096;
            #pragma unroll
            for (int e = 0; e < 2; e++) {
                int ch = w + 4 * e;
                gld16(vt + ch * 512, Vs + ch * 512);
                gld16(Kb + (size_t)(J0t + ch * 8 + ln8) * 2048 + koff, Ks + ch * 512);
            }
        };
        auto stageR = [&](int u) {
            bf16* rd = Rs[u % 3];
            #pragma unroll
            for (int e = 0; e < 2; e++) {
                int ch = w + 4 * e;
                int rrow = min(RB + u * 64 + ch * 8 + ln8, 2047);  // OOB -> masked pairs only
                gld16(Rk + (size_t)rrow * 1024 + rcol, rd + ch * 512);
            }
        };

        short8 aqw[2], aqr[2];
        {
            const bf16* qp = Qw + ((size_t)(qbase + l16) * 2 + b) * 1024 + n * 64 + quad * 8;
            aqw[0] = *reinterpret_cast<const short8*>(qp);
            aqw[1] = *reinterpret_cast<const short8*>(qp + 32);
            const bf16* qp2 = Qr + ((size_t)(qbase + l16) * 2 + b) * 1024 + n * 64 + quad * 8;
            aqr[0] = *reinterpret_cast<const short8*>(qp2);
            aqr[1] = *reinterpret_cast<const short8*>(qp2 + 32);
        }

        f32x4 O[4];
        #pragma unroll
        for (int d = 0; d < 4; d++) O[d] = (f32x4){0.f, 0.f, 0.f, 0.f};
        float m_run = -1e30f;
        float pl[4] = {0.f, 0.f, 0.f, 0.f};

        // segment prologue: (sg>0) make sure nobody still reads old buffers,
        // then seed the R ring with halves jb, jb+1.
        if (sg) {
            asm volatile("s_waitcnt vmcnt(0)" ::: "memory");
            __builtin_amdgcn_s_barrier();
        }
        stageR(jb); stageR(jb + 1);

        for (int j = jb; j < je; j++) {
            const int J0 = j * 64;

            // publish R(j+1) (and all older): issued a full tile ago -> ~free
            asm volatile("s_waitcnt vmcnt(0)" ::: "memory");
            __builtin_amdgcn_s_barrier();

            // issue this tile's V,K and next-next R half
            stageKV(j);
            stageR(j + 2);

            const bf16* R0 = Rs[j % 3];
            const bf16* R1 = Rs[(j + 1) % 3];

            // ---- BD window GEMM from R halves (covers K/V flight time) ----
            #pragma unroll
            for (int s = 0; s < 5; s++) {
                int rb2 = rbl + 16 * s;                   // 0..112, 16-aligned
                const bf16* Rb = (rb2 & 64) ? R1 : R0;
                int rh = (rb2 & 63) + l16;
                short8 b0 = *reinterpret_cast<const short8*>(&Rb[rh * 64 + q0]);
                short8 b1 = *reinterpret_cast<const short8*>(&Rb[rh * 64 + q1]);
                f32x4 acc = (f32x4){0.f, 0.f, 0.f, 0.f};
                __builtin_amdgcn_s_setprio(1);
                acc = MFMA16(aqr[0], b0, acc);
                acc = MFMA16(aqr[1], b1, acc);
                __builtin_amdgcn_s_setprio(0);
                #pragma unroll
                for (int r = 0; r < 4; r++)
                    WP[(quad * 4 + r) * 82 + 16 * s + l16] = f2bs(acc[r]);
            }

            // publish V(j),K(j); leave R(j+2) (2 newest ops) in flight
            asm volatile("s_waitcnt vmcnt(2)" ::: "memory");
            __builtin_amdgcn_s_barrier();

            // ---- AC GEMM from Ks + score assembly (pre-scaled, mask last tile only) ----
            float sv[4][4];
            #pragma unroll
            for (int n16 = 0; n16 < 4; n16++) {
                int kr = 16 * n16 + l16;
                short8 k0 = *reinterpret_cast<const short8*>(&Ks[kr * 64 + q0]);
                short8 k1 = *reinterpret_cast<const short8*>(&Ks[kr * 64 + q1]);
                f32x4 acc = (f32x4){0.f, 0.f, 0.f, 0.f};
                __builtin_amdgcn_s_setprio(1);
                acc = MFMA16(aqw[0], k0, acc);
                acc = MFMA16(aqw[1], k1, acc);
                __builtin_amdgcn_s_setprio(0);
                #pragma unroll
                for (int r = 0; r < 4; r++) {
                    int row = quad * 4 + r, col = 16 * n16 + l16;
                    sv[n16][r] = acc[r] + s2f(WP[row * 82 + col - row + 15]);
                }
            }
            if (j == jlast) {
                #pragma unroll
                for (int n16 = 0; n16 < 4; n16++)
                    #pragma unroll
                    for (int r = 0; r < 4; r++) {
                        int row = quad * 4 + r, col = 16 * n16 + l16;
                        if (J0 + col > qbase + row + MEMLEN) sv[n16][r] = -1e30f;
                    }
            }

            // ---- online softmax in log2 domain (defer-max, THR=11.5 bits) ----
            float mx = sv[0][0];
            #pragma unroll
            for (int n16 = 0; n16 < 4; n16++)
                #pragma unroll
                for (int r = 0; r < 4; r++) mx = fmaxf(mx, sv[n16][r]);
            #pragma unroll
            for (int msk = 1; msk < 16; msk <<= 1) mx = fmaxf(mx, __shfl_xor(mx, msk));
            if (mx > m_run + 11.5f) {
                const float alpha = fexp2(m_run - mx);
                m_run = mx;
                #pragma unroll
                for (int r = 0; r < 4; r++) pl[r] *= alpha;
                #pragma unroll
                for (int d = 0; d < 4; d++)
                    #pragma unroll
                    for (int r = 0; r < 4; r++) O[d][r] *= alpha;
            }
            #pragma unroll
            for (int n16 = 0; n16 < 4; n16++)
                #pragma unroll
                for (int r = 0; r < 4; r++) sv[n16][r] = fexp2(sv[n16][r] - m_run);
            #pragma unroll
            for (int r = 0; r < 4; r++)
                pl[r] += sv[0][r] + sv[1][r] + sv[2][r] + sv[3][r];

            // ---- P -> per-wave LDS bf16 (stride 72), read back as A-frags ----
            #pragma unroll
            for (int n16 = 0; n16 < 4; n16++)
                #pragma unroll
                for (int r = 0; r < 4; r++)
                    WP[(quad * 4 + r) * 72 + 16 * n16 + l16] = f2bs(sv[n16][r]);
            short8 ap0 = *reinterpret_cast<short8*>(&WP[l16 * 72 + quad * 8]);
            short8 ap1 = *reinterpret_cast<short8*>(&WP[l16 * 72 + 32 + quad * 8]);

            // ---- PV from Vs (fragment layout: linear, conflict-free) ----
            __builtin_amdgcn_s_setprio(1);
            #pragma unroll
            for (int ds = 0; ds < 4; ds++) {
                short8 v0 = *reinterpret_cast<const short8*>(&Vs[(ds * 2 + 0) * 512 + lane * 8]);
                short8 v1 = *reinterpret_cast<const short8*>(&Vs[(ds * 2 + 1) * 512 + lane * 8]);
                O[ds] = MFMA16(ap0, v0, O[ds]);
                O[ds] = MFMA16(ap1, v1, O[ds]);
            }
            __builtin_amdgcn_s_setprio(0);
        }

        // ---- flush segment partial (UNNORMALIZED O + (m,l)), m in log2 domain ----
        float lr[4];
        #pragma unroll
        for (int r = 0; r < 4; r++) {
            float s = pl[r];
            #pragma unroll
            for (int msk = 1; msk < 16; msk <<= 1) s += __shfl_xor(s, msk);
            lr[r] = s;
        }
        if (l16 == 0) {
            #pragma unroll
            for (int r = 0; r < 4; r++) {
                int q = qbase + quad * 4 + r;
                ML[(size_t)slot * 32768 + (q * 2 + b) * 16 + n] =
                    make_float2(m_run, lr[r]);
            }
        }
        float* Od = slot ? O1g : O0g;
        #pragma unroll
        for (int ds = 0; ds < 4; ds++)
            #pragma unroll
            for (int r = 0; r < 4; r++) {
                int q = qbase + quad * 4 + r;
                Od[((size_t)q * 2 + b) * 1024 + n * 64 + 16 * ds + l16] = O[ds][r];
            }
    }
}

// ---------------- FUSED combine + Wo GEMM, split-K2 ----------------
// A[row, c] = (O0[row,c]*e0 + O1[row,c]*e1) * inv  computed during reg-staging
// (e0,e1,inv from ML[row, n=c>>6]; rows of block bm=0 have only slot0).
// Grid 256 1D, remapped so each XCD owns 2 bm-panels (16 blocks each): the x8 bn
// redundancy of A-combine re-reads is then served by that XCD's 4MB L2.
// z (K-half) -> C0/C1, summed with the residual in ln_res.
__global__ __launch_bounds__(256)
void wo_gemm(const float* __restrict__ O0, const float* __restrict__ O1,
             const float2* __restrict__ ML, const bf16* __restrict__ Wot,
             float* __restrict__ C0, float* __restrict__ C1) {
    const int lid = blockIdx.x;
    const int xcd = lid & 7, q = lid >> 3;            // q 0..31
    const int bmi = xcd * 2 + (q & 1);                // 0..15
    const int bni = (q >> 1) & 7;                     // 0..7
    const int z = q >> 4;                             // 0..1
    const int bm = bmi * 128, bn = bni * 128, kz = z * 512;
    float* Cfz = z ? C1 : C0;
    const bool two = (bmi != 0);                      // block-uniform: i0==0 rows have only slot0

    __shared__ bf16 As[2][128 * 32];
    __shared__ bf16 Bs[2][128 * 32];
    const int t = threadIdx.x;
    const int w = t >> 6, lane = t & 63, quad = lane >> 4, l16 = lane & 15;
    const int wm = (w >> 1) * 64, wn = (w & 1) * 64;
    const int lrow = lane >> 2, lcol = (lane & 3) * 8;
    const int arow = t >> 1, acl = (t & 1) * 16;      // A-stage: 2 thr/row, 16 cols each
    const int grow = bm + arow;

    auto stageA = [&](int k0, int buf) {
        const int c = kz + k0 + acl;                  // 16-aligned, within one 64-block
        const int n = c >> 6;
        const float2 a0 = ML[grow * 16 + n];
        const float2 a1 = two ? ML[32768 + grow * 16 + n] : make_float2(-3e38f, 0.f);
        const float m = fmaxf(a0.x, a1.x);
        const float e0 = fexp2(a0.x - m);
        const float e1 = fexp2(a1.x - m);
        const float inv = 1.f / (a0.y * e0 + a1.y * e1);
        const f32x4* p0 = reinterpret_cast<const f32x4*>(&O0[(size_t)grow * 1024 + c]);
        const f32x4* p1 = reinterpret_cast<const f32x4*>(&O1[(size_t)grow * 1024 + c]);
        short o[16];
        #pragma unroll
        for (int u = 0; u < 4; u++) {
            f32x4 v0 = p0[u];
            f32x4 v1 = two ? p1[u] : (f32x4){0.f, 0.f, 0.f, 0.f};
            #pragma unroll
            for (int jj = 0; jj < 4; jj++)
                o[u * 4 + jj] = f2bs((v0[jj] * e0 + v1[jj] * e1) * inv);
        }
        *reinterpret_cast<short8*>(&As[buf][arow * 32 + acl])     = *reinterpret_cast<short8*>(o);
        *reinterpret_cast<short8*>(&As[buf][arow * 32 + acl + 8]) = *reinterpret_cast<short8*>(o + 8);
    };
    auto stageB = [&](int k0, int buf) {
        #pragma unroll
        for (int e = 0; e < 2; e++) {
            int ch = w + 4 * e;
            int row = ch * 16 + lrow;
            gld16(Wot + (size_t)(bn + row) * 1024 + kz + k0 + lcol, Bs[buf] + ch * 512);
        }
    };

    f32x4 acc[4][4];
    #pragma unroll
    for (int mt = 0; mt < 4; mt++)
        #pragma unroll
        for (int nt = 0; nt < 4; nt++) acc[mt][nt] = (f32x4){0.f, 0.f, 0.f, 0.f};

    stageB(0, 0);
    stageA(0, 0);
    const int NK = 16;                                // K=512 per z, BK=32
    for (int kk = 0; kk < NK; kk++) {
        __syncthreads();                              // publish stage(kk)
        if (kk + 1 < NK) { stageB((kk + 1) << 5, (kk + 1) & 1); stageA((kk + 1) << 5, (kk + 1) & 1); }
        const bf16* A_ = As[kk & 1];
        const bf16* B_ = Bs[kk & 1];
        short8 af[4], bfr[4];
        #pragma unroll
        for (int mt = 0; mt < 4; mt++)
            af[mt] = *reinterpret_cast<const short8*>(&A_[(wm + 16 * mt + l16) * 32 + quad * 8]);
        #pragma unroll
        for (int nt = 0; nt < 4; nt++)
            bfr[nt] = *reinterpret_cast<const short8*>(&B_[(wn + 16 * nt + l16) * 32 + quad * 8]);
        #pragma unroll
        for (int mt = 0; mt < 4; mt++)
            #pragma unroll
            for (int nt = 0; nt < 4; nt++)
                acc[mt][nt] = MFMA16(af[mt], bfr[nt], acc[mt][nt]);
    }

    #pragma unroll
    for (int mt = 0; mt < 4; mt++)
        #pragma unroll
        for (int nt = 0; nt < 4; nt++)
            #pragma unroll
            for (int r = 0; r < 4; r++) {
                int m = bm + wm + 16 * mt + quad * 4 + r;
                int c = bn + wn + 16 * nt + l16;
                Cfz[(size_t)m * 1024 + c] = acc[mt][nt][r];
            }
}

// ---------------- out = LN(ao0 + ao1 + w), f32; wave-shuffle reduction ----------------
__global__ __launch_bounds__(256)
void ln_res(const float* __restrict__ ao0, const float* __restrict__ ao1,
            const float* __restrict__ w, const float* __restrict__ gamma,
            const float* __restrict__ beta, float* __restrict__ out) {
    const int m = blockIdx.x;
    const int t = threadIdx.x;
    const int wv = t >> 6, lane = t & 63;
    __shared__ float red[8];
    float x[4];
    #pragma unroll
    for (int e = 0; e < 4; e++) {
        int c = e * 256 + t;
        x[e] = ao0[(size_t)m * DMODEL + c] + ao1[(size_t)m * DMODEL + c]
             + w[(size_t)m * DMODEL + c];
    }
    float s = x[0] + x[1] + x[2] + x[3];
    #pragma unroll
    for (int msk = 1; msk < 64; msk <<= 1) s += __shfl_xor(s, msk);
    if (lane == 0) red[wv] = s;
    __syncthreads();
    const float mu = (red[0] + red[1] + red[2] + red[3]) * (1.f / 1024.f);
    float s2 = 0.f;
    #pragma unroll
    for (int e = 0; e < 4; e++) { float dx = x[e] - mu; s2 += dx * dx; }
    #pragma unroll
    for (int msk = 1; msk < 64; msk <<= 1) s2 += __shfl_xor(s2, msk);
    if (lane == 0) red[4 + wv] = s2;
    __syncthreads();
    const float rstd = rsqrtf((red[4] + red[5] + red[6] + red[7]) * (1.f / 1024.f) + LN_EPS);
    #pragma unroll
    for (int e = 0; e < 4; e++) {
        int c = e * 256 + t;
        out[(size_t)m * DMODEL + c] = (x[e] - mu) * rstd * gamma[c] + beta[c];
    }
}

extern "C" void kernel_launch(void* const* d_in, const int* in_sizes, int n_in,
                              void* d_out, int out_size, void* d_ws, size_t ws_size,
                              hipStream_t stream) {
    const float* w        = (const float*)d_in[0];
    const float* r        = (const float*)d_in[1];
    const float* r_w_bias = (const float*)d_in[2];
    const float* r_r_bias = (const float*)d_in[3];
    const float* mems     = (const float*)d_in[4];
    // d_in[5] attn_mask: deterministic (j <= i+MEMLEN), applied analytically
    const float* W_qkv    = (const float*)d_in[6];
    const float* W_r      = (const float*)d_in[7];
    const float* W_o      = (const float*)d_in[8];
    const float* gamma    = (const float*)d_in[9];
    const float* beta     = (const float*)d_in[10];
    float* out = (float*)d_out;

    // Workspace (~54 MB). Dead-region aliases:
    //   Opart0 (f32 [2048,1024]) = Abf         (dead after QKV GEMM)
    //   Opart1 (f32 [2048,1024]) = Wqkvt+Wrt   (dead after QKV GEMM)
    //   ML     (f32x2 [2,2048,16]) = rbf       (dead after QKV GEMM)
    //   attn_out0 f32 = Kb region, attn_out1 f32 = Vt region (dead after attn;
    //   wo_gemm READS O0/O1 so it cannot write over them)
    bf16* Abf    = (bf16*)d_ws;                    // [4096,1024] cat rows m=j*2+b
    bf16* Wqkvt  = Abf   + (size_t)4096 * 1024;    // [3072,1024]
    bf16* Wrt    = Wqkvt + (size_t)3072 * 1024;    // [1024,1024]
    bf16* Wot    = Wrt   + (size_t)1024 * 1024;    // [1024,1024]
    bf16* rbf    = Wot   + (size_t)1024 * 1024;    // [2048,1024]
    bf16* Qw     = rbf   + (size_t)2048 * 1024;    // [2048,1024] rows i*2+b
    bf16* Qr     = Qw    + (size_t)2048 * 1024;
    bf16* Kb     = Qr    + (size_t)2048 * 1024;    // [4096,1024] rows j*2+b
    bf16* Vt     = Kb    + (size_t)4096 * 1024;    // [2048,2048] fragment layout
    bf16* Rk     = Vt    + (size_t)2048 * 2048;    // [2048,1024]
    float* Opart0   = (float*)Abf;                 // [2048,1024] f32 (alias)
    float* Opart1   = (float*)Wqkvt;               // [2048,1024] f32 (alias)
    float2* ML      = (float2*)rbf;                // [2,2048,16] (alias)
    float* attn_out0 = (float*)Kb;                 // split-K half 0 (8MB region)
    float* attn_out1 = (float*)Vt;                 // split-K half 1 (8MB region)

    dim3 b256(256);
    prep<<<dim3(7424), b256, 0, stream>>>(mems, w, r, W_qkv, W_r, W_o,
                                          Abf, rbf, Wqkvt, Wrt, Wot);
    // QKV GEMM (depth-2 pipelined; + recycled Rk tiles, + V fragment-layout writes)
    gemm_qkv<<<dim3(32, 24), b256, 0, stream>>>(
        Abf, Wqkvt, rbf, Wrt, r_w_bias, r_r_bias, Qw, Qr, Kb, Vt, Rk);
    attn_mfma<<<dim3(768), b256, 0, stream>>>(Qw, Qr, Kb, Vt, Rk,
                                              Opart0, Opart1, ML);
    // fused combine + Wo GEMM (split-K2, XCD-clustered bm panels)
    wo_gemm<<<dim3(256), b256, 0, stream>>>(Opart0, Opart1, ML, Wot,
                                            attn_out0, attn_out1);
    ln_res<<<dim3(QLEN * BSZ), b256, 0, stream>>>(attn_out0, attn_out1, w,
                                                  gamma, beta, out);
}